// Round 2
// baseline (3151.281 us; speedup 1.0000x reference)
//
#include <hip/hip_runtime.h>
#include <hip/hip_bf16.h>

#define TT   128
#define BATCH 1024
#define INDIM 512
#define HIDD  1024
#define NCLS  10

typedef __bf16 bf16x8 __attribute__((ext_vector_type(8)));
typedef float  f32x4  __attribute__((ext_vector_type(4)));
typedef unsigned short u16x8 __attribute__((ext_vector_type(8)));

__device__ __forceinline__ unsigned short bf16b(float f) {
    __hip_bfloat16 h = __float2bfloat16(f);
    return __builtin_bit_cast(unsigned short, h);
}

__device__ __forceinline__ float tanh_fast(float x) {
    float e = __expf(2.0f * x);
    return 1.0f - 2.0f * __builtin_amdgcn_rcpf(e + 1.0f);
}

// ---------------------------------------------------------------------------
// Prep: W -> transposed bf16 hi/lo pairs (unchanged from R1, verified).
// ---------------------------------------------------------------------------
__global__ __launch_bounds__(256) void prep_kernel(
    const float* __restrict__ Whh, const float* __restrict__ Wxh,
    __hip_bfloat16* __restrict__ WhhT_hi, __hip_bfloat16* __restrict__ WhhT_lo,
    __hip_bfloat16* __restrict__ WxhT_hi, __hip_bfloat16* __restrict__ WxhT_lo)
{
    __shared__ float tl[64][68];
    int bid = blockIdx.x, tid = threadIdx.x;
    const float* src; int N, k0, n0, dstride;
    __hip_bfloat16 *dhi, *dlo;
    if (bid < 256) { src = Whh; N = 1024; k0 = (bid >> 4) << 6; n0 = (bid & 15) << 6;
                     dhi = WhhT_hi; dlo = WhhT_lo; dstride = 1024; }
    else { int b = bid - 256; src = Wxh; N = 1024; k0 = (b >> 4) << 6; n0 = (b & 15) << 6;
           dhi = WxhT_hi; dlo = WxhT_lo; dstride = 512; }

    int r = tid >> 2, c0 = (tid & 3) << 4;
    const float* s = src + (size_t)(k0 + r) * N + n0 + c0;
#pragma unroll
    for (int j = 0; j < 4; ++j)
        *(float4*)&tl[r][c0 + j * 4] = *(const float4*)(s + j * 4);
    __syncthreads();

    int rn = tid >> 2, ck0 = (tid & 3) << 4;
    u16x8 hi0, hi1, lo0, lo1;
#pragma unroll
    for (int j = 0; j < 16; ++j) {
        float w = tl[ck0 + j][rn];
        unsigned short hb = bf16b(w);
        float hf = __bfloat162float(__builtin_bit_cast(__hip_bfloat16, hb));
        unsigned short lb = bf16b(w - hf);
        if (j < 8) { hi0[j] = hb; lo0[j] = lb; }
        else       { hi1[j - 8] = hb; lo1[j - 8] = lb; }
    }
    size_t o = (size_t)(n0 + rn) * dstride + k0 + ck0;
    *(u16x8*)(void*)(dhi + o)     = hi0;
    *(u16x8*)(void*)(dhi + o + 8) = hi1;
    *(u16x8*)(void*)(dlo + o)     = lo0;
    *(u16x8*)(void*)(dlo + o + 8) = lo1;
}

// ---------------------------------------------------------------------------
__global__ __launch_bounds__(256) void convx_kernel(
    const float* __restrict__ x, __hip_bfloat16* __restrict__ xs, int t)
{
    int bid = blockIdx.x, tid = threadIdx.x;
    int row = (bid << 2) + (tid >> 6);
    int i   = (tid & 63) << 3;
    const float* s = x + (size_t)row * (TT * INDIM) + (size_t)t * INDIM + i;
    float4 a = *(const float4*)s, b = *(const float4*)(s + 4);
    u16x8 o;
    o[0]=bf16b(a.x); o[1]=bf16b(a.y); o[2]=bf16b(a.z); o[3]=bf16b(a.w);
    o[4]=bf16b(b.x); o[5]=bf16b(b.y); o[6]=bf16b(b.z); o[7]=bf16b(b.w);
    *(u16x8*)(void*)(xs + (size_t)row * INDIM + i) = o;
}

__global__ __launch_bounds__(256) void zeroh_kernel(__hip_bfloat16* __restrict__ h)
{
    int i = (blockIdx.x * 256 + threadIdx.x) << 3;
    u16x8 z = {0,0,0,0,0,0,0,0};
    *(u16x8*)(void*)(h + i) = z;
}

// ---------------------------------------------------------------------------
// Step kernel, R2: A (h rows / x rows) loaded straight to VGPRs (16B frags);
// only B hi/lo staged via global_load_lds (XOR-swizzled via source address).
// XCD-aware bid swizzle: XCD k owns bx in {2k, 2k+1} -> weights L2-resident.
// ---------------------------------------------------------------------------
__device__ __forceinline__ void stage_tile(const __hip_bfloat16* src, int stride,
                                           char* ldsbase, int tid)
{
#pragma unroll
    for (int i = 0; i < 2; ++i) {
        int r  = (i << 5) + (tid >> 3);
        int cb = (tid & 7) ^ (r & 7);
        const void* g = (const void*)(src + r * stride + (cb << 3));
        void* l = (void*)(ldsbase + ((tid & 192) << 4) + (i << 12));
        __builtin_amdgcn_global_load_lds((const __attribute__((address_space(1))) void*)g,
                                         (__attribute__((address_space(3))) void*)l,
                                         16, 0, 0);
    }
}

__device__ __forceinline__ bf16x8 fragB(const char* tile, int row, int cb)
{
    return *(const bf16x8*)(tile + (row << 7) + ((cb ^ (row & 7)) << 4));
}

__global__ __launch_bounds__(256, 1) void step_kernel(
    const __hip_bfloat16* __restrict__ h_prev, __hip_bfloat16* __restrict__ h_next,
    const __hip_bfloat16* __restrict__ xs_cur, __hip_bfloat16* __restrict__ xs_next,
    const __hip_bfloat16* __restrict__ WhhT_hi, const __hip_bfloat16* __restrict__ WhhT_lo,
    const __hip_bfloat16* __restrict__ WxhT_hi, const __hip_bfloat16* __restrict__ WxhT_lo,
    const float* __restrict__ x, const float* __restrict__ b_xh, const float* __restrict__ b_hh,
    int t, int last)
{
    __shared__ char smem[32768];                 // 2 bufs x (Bhi + Blo) x 8KB
    int tid  = threadIdx.x;
    int bid  = blockIdx.x;
    // XCD swizzle: default assignment is bid%8 -> XCD, so give XCD k the
    // blocks with bx in {2k,2k+1}: weight strips stay resident in that L2.
    int xcd = bid & 7, idx = bid >> 3;
    int bx = (xcd << 1) | (idx >> 4), by = idx & 15;
    int bx64 = bx << 6, by64 = by << 6;
    int lane = tid & 63, wave = tid >> 6;
    int wm32 = (wave >> 1) << 5, wn32 = (wave & 1) << 5;
    int ar = lane & 15, kg = lane >> 4;

    // Early-issue next-slice x loads; converted+stored in the tail.
    int crow = (bid << 2) + wave, ci = lane << 3;
    float4 cv0, cv1;
    if (!last) {
        const float* cs = x + (size_t)crow * (TT * INDIM) + (size_t)(t + 1) * INDIM + ci;
        cv0 = *(const float4*)cs; cv1 = *(const float4*)(cs + 4);
    }

    // Per-lane A base pointers: this lane's rows, 16B frag at k = kg*8.
    const __hip_bfloat16* hb = h_prev + (size_t)(by64 + wm32 + ar) * HIDD + (kg << 3);
    const __hip_bfloat16* xb = xs_cur + (size_t)(by64 + wm32 + ar) * INDIM + (kg << 3);

    f32x4 acc00 = {0,0,0,0}, acc01 = {0,0,0,0}, acc10 = {0,0,0,0}, acc11 = {0,0,0,0};
    bf16x8 aa[2][4];   // [buf][a0_ks0, a1_ks0, a0_ks1, a1_ks1]

    auto loadA = [&](bf16x8* a, int c) {
        if (c < 16) {
            const __hip_bfloat16* p = hb + (c << 6);
            a[0] = *(const bf16x8*)(p);
            a[1] = *(const bf16x8*)(p + (HIDD << 4));     // +16 rows
            a[2] = *(const bf16x8*)(p + 32);              // ks=1: +32 elems
            a[3] = *(const bf16x8*)(p + (HIDD << 4) + 32);
        } else {
            const __hip_bfloat16* p = xb + ((c - 16) << 6);
            a[0] = *(const bf16x8*)(p);
            a[1] = *(const bf16x8*)(p + (INDIM << 4));
            a[2] = *(const bf16x8*)(p + 32);
            a[3] = *(const bf16x8*)(p + (INDIM << 4) + 32);
        }
    };
    auto stageB = [&](char* buf, int c) {
        if (c < 16) {
            stage_tile(WhhT_hi + (size_t)bx64 * HIDD + (c << 6), HIDD, buf,        tid);
            stage_tile(WhhT_lo + (size_t)bx64 * HIDD + (c << 6), HIDD, buf + 8192, tid);
        } else {
            stage_tile(WxhT_hi + (size_t)bx64 * INDIM + ((c - 16) << 6), INDIM, buf,        tid);
            stage_tile(WxhT_lo + (size_t)bx64 * INDIM + ((c - 16) << 6), INDIM, buf + 8192, tid);
        }
    };

    loadA(aa[0], 0);
    stageB(smem, 0);
    __syncthreads();

#pragma unroll
    for (int c = 0; c < 24; ++c) {
        const char* Bh = smem + (c & 1) * 16384;
        const char* Bl = Bh + 8192;
        if (c < 23) {
            loadA(aa[(c + 1) & 1], c + 1);
            stageB(smem + ((c + 1) & 1) * 16384, c + 1);
        }
        const bf16x8* a = aa[c & 1];
#pragma unroll
        for (int ks = 0; ks < 2; ++ks) {
            int cb = (ks << 2) + kg;
            bf16x8 a0  = a[(ks << 1)];
            bf16x8 a1  = a[(ks << 1) + 1];
            bf16x8 bh0 = fragB(Bh, wn32 + ar,      cb);
            bf16x8 bh1 = fragB(Bh, wn32 + 16 + ar, cb);
            bf16x8 bl0 = fragB(Bl, wn32 + ar,      cb);
            bf16x8 bl1 = fragB(Bl, wn32 + 16 + ar, cb);
            acc00 = __builtin_amdgcn_mfma_f32_16x16x32_bf16(a0, bh0, acc00, 0, 0, 0);
            acc00 = __builtin_amdgcn_mfma_f32_16x16x32_bf16(a0, bl0, acc00, 0, 0, 0);
            acc01 = __builtin_amdgcn_mfma_f32_16x16x32_bf16(a0, bh1, acc01, 0, 0, 0);
            acc01 = __builtin_amdgcn_mfma_f32_16x16x32_bf16(a0, bl1, acc01, 0, 0, 0);
            acc10 = __builtin_amdgcn_mfma_f32_16x16x32_bf16(a1, bh0, acc10, 0, 0, 0);
            acc10 = __builtin_amdgcn_mfma_f32_16x16x32_bf16(a1, bl0, acc10, 0, 0, 0);
            acc11 = __builtin_amdgcn_mfma_f32_16x16x32_bf16(a1, bh1, acc11, 0, 0, 0);
            acc11 = __builtin_amdgcn_mfma_f32_16x16x32_bf16(a1, bl1, acc11, 0, 0, 0);
        }
        __syncthreads();
    }

    // Epilogue: + biases, tanh, store bf16. D: col=lane&15, row=(lane>>4)*4+j.
    int colb = bx64 + wn32 + (lane & 15);
    int rowb = by64 + wm32 + ((lane >> 4) << 2);
#pragma unroll
    for (int mf = 0; mf < 2; ++mf) {
#pragma unroll
        for (int nf = 0; nf < 2; ++nf) {
            f32x4 a = mf ? (nf ? acc11 : acc10) : (nf ? acc01 : acc00);
            int col = colb + (nf << 4);
            float bs = b_xh[col] + b_hh[col];
#pragma unroll
            for (int j = 0; j < 4; ++j) {
                int row = rowb + (mf << 4) + j;
                float v = tanh_fast(a[j] + bs);
                h_next[(size_t)row * HIDD + col] = __float2bfloat16(v);
            }
        }
    }

    if (!last) {
        u16x8 o;
        o[0]=bf16b(cv0.x); o[1]=bf16b(cv0.y); o[2]=bf16b(cv0.z); o[3]=bf16b(cv0.w);
        o[4]=bf16b(cv1.x); o[5]=bf16b(cv1.y); o[6]=bf16b(cv1.z); o[7]=bf16b(cv1.w);
        *(u16x8*)(void*)(xs_next + (size_t)crow * INDIM + ci) = o;
    }
}

// ---------------------------------------------------------------------------
__global__ __launch_bounds__(64) void out_kernel(
    const __hip_bfloat16* __restrict__ h, const float* __restrict__ Why,
    const float* __restrict__ b_y, float* __restrict__ out)
{
    int b = blockIdx.x, lane = threadIdx.x;
    float acc[NCLS];
#pragma unroll
    for (int c = 0; c < NCLS; ++c) acc[c] = 0.f;
    for (int kk = 0; kk < 16; ++kk) {
        int k = (kk << 6) + lane;
        float hv = __bfloat162float(h[(size_t)b * HIDD + k]);
#pragma unroll
        for (int c = 0; c < NCLS; ++c) acc[c] += hv * Why[(size_t)k * NCLS + c];
    }
#pragma unroll
    for (int c = 0; c < NCLS; ++c) {
        float v = acc[c];
#pragma unroll
        for (int off = 32; off > 0; off >>= 1) v += __shfl_down(v, off);
        if (lane == 0) out[(size_t)b * NCLS + c] = v + b_y[c];
    }
}

// ---------------------------------------------------------------------------
extern "C" void kernel_launch(void* const* d_in, const int* in_sizes, int n_in,
                              void* d_out, int out_size, void* d_ws, size_t ws_size,
                              hipStream_t stream)
{
    const float* x    = (const float*)d_in[0];
    const float* Wxh  = (const float*)d_in[1];
    const float* b_xh = (const float*)d_in[2];
    const float* Whh  = (const float*)d_in[3];
    const float* b_hh = (const float*)d_in[4];
    const float* Why  = (const float*)d_in[5];
    const float* b_y  = (const float*)d_in[6];
    float* out = (float*)d_out;

    char* ws = (char*)d_ws;                       // 12 MB used
    __hip_bfloat16* WhhT_hi = (__hip_bfloat16*)(ws);
    __hip_bfloat16* WhhT_lo = (__hip_bfloat16*)(ws + (2u << 20));
    __hip_bfloat16* WxhT_hi = (__hip_bfloat16*)(ws + (4u << 20));
    __hip_bfloat16* WxhT_lo = (__hip_bfloat16*)(ws + (5u << 20));
    __hip_bfloat16* h0      = (__hip_bfloat16*)(ws + (6u << 20));
    __hip_bfloat16* h1      = (__hip_bfloat16*)(ws + (8u << 20));
    __hip_bfloat16* xs0     = (__hip_bfloat16*)(ws + (10u << 20));
    __hip_bfloat16* xs1     = (__hip_bfloat16*)(ws + (11u << 20));

    prep_kernel<<<384, 256, 0, stream>>>(Whh, Wxh, WhhT_hi, WhhT_lo, WxhT_hi, WxhT_lo);
    convx_kernel<<<256, 256, 0, stream>>>(x, xs0, 0);
    zeroh_kernel<<<512, 256, 0, stream>>>(h0);    // h0 = 0 (d_ws is poisoned)

    __hip_bfloat16* hp[2] = {h0, h1};
    __hip_bfloat16* xs[2] = {xs0, xs1};
    for (int t = 0; t < TT; ++t) {
        step_kernel<<<256, 256, 0, stream>>>(
            hp[t & 1], hp[(t + 1) & 1], xs[t & 1], xs[(t + 1) & 1],
            WhhT_hi, WhhT_lo, WxhT_hi, WxhT_lo,
            x, b_xh, b_hh, t, (t == TT - 1) ? 1 : 0);
    }
    out_kernel<<<1024, 64, 0, stream>>>(hp[0], Why, b_y, out);
}